// Round 1
// baseline (1319.965 us; speedup 1.0000x reference)
//
#include <hip/hip_runtime.h>
#include <hip/hip_bf16.h>
#include <math.h>
#include <cstdint>

typedef unsigned long long u64;

// ---------------------------------------------------------------------------
// Sizes
// ---------------------------------------------------------------------------
#define HH 64
#define WW 64
#define NPIX 4096          // 64*64
#define NANCH 36864        // 4096*9
#define SEG 65536          // padded per-image sort segment
#define N_PRE 6000
#define N_POST 300

// output float offsets
#define O0 0               // rpn_locs  2*36864*4 = 294912
#define O1 294912          // rpn_scores 2*36864*2 = 147456
#define O2 442368          // rois 2*300*4 = 2400
#define O3 444768          // roi_indices 600
#define O4 445368          // anchor 147456
#define O5 592824          // vmask 600

// workspace float offsets
#define WS_WT 0                       // 2359296  (w transposed [c*9+t][512])
#define WS_WSLT 2359296               // 32768    ([c][64] loc(36)+score(18)+pad)
#define WS_WSLB (WS_WSLT + 32768)     // 64
#define WS_H (WS_WSLB + 64)           // 4194304  h buffer
#define WS_FG (WS_H + 4194304)        // 73728
#define WS_SC (WS_FG + 73728)         // 73728
#define WS_ROI (WS_SC + 73728)        // 294912 (float4 aligned)
#define WS_KEYS (WS_ROI + 294912)     // 131072 u64

// ---------------------------------------------------------------------------
// 0. weight prep: transpose conv weights to [c*9+t][512]; pack head weights
// ---------------------------------------------------------------------------
__global__ __launch_bounds__(256) void prep_weights(
    const float* __restrict__ w, const float* __restrict__ lw,
    const float* __restrict__ sw, const float* __restrict__ lb,
    const float* __restrict__ sb, float* __restrict__ wt,
    float* __restrict__ wslt, float* __restrict__ wslb) {
  int e = blockIdx.x * 256 + threadIdx.x;
  if (e < 2359296) {
    int row = e >> 9, o = e & 511;
    int c = row / 9, t = row - c * 9;
    wt[e] = w[((size_t)o * 512 + c) * 9 + t];
  } else if (e < 2359296 + 32768) {
    int e2 = e - 2359296;
    int c = e2 >> 6, o = e2 & 63;
    float v = 0.f;
    if (o < 36) v = lw[o * 512 + c];
    else if (o < 54) v = sw[(o - 36) * 512 + c];
    wslt[e2] = v;
  } else if (e < 2359296 + 32768 + 64) {
    int o = e - 2359296 - 32768;
    float v = 0.f;
    if (o < 36) v = lb[o];
    else if (o < 54) v = sb[o - 36];
    wslb[o] = v;
  }
}

// ---------------------------------------------------------------------------
// 1. 3x3 conv 512->512 SAME + bias + relu.
// grid (16 spatial tiles, 8 o-groups, 2 n), block 256.
// Block: 64 o x (16x16) spatial. Thread: 8 o x 8 x.
// ---------------------------------------------------------------------------
__global__ __launch_bounds__(256) void conv3x3(
    const float* __restrict__ xin, const float* __restrict__ wt,
    const float* __restrict__ bias, float* __restrict__ hout) {
  __shared__ float sIn[2880];   // [8c][18y][20x]
  __shared__ float sW[4608];    // [72][64]
  const int tid = threadIdx.x;
  const int tile = blockIdx.x, og = blockIdx.y, n = blockIdx.z;
  const int ty0 = (tile >> 2) << 4, tx0 = (tile & 3) << 4;
  const int o0 = og << 6;
  const int ot = tid >> 5;          // 0..7
  const int st = tid & 31;
  const int sy = st >> 1;           // 0..15
  const int x0l = (st & 1) << 3;    // 0 or 8

  float acc[8][8];
#pragma unroll
  for (int j = 0; j < 8; ++j)
#pragma unroll
    for (int d = 0; d < 8; ++d) acc[j][d] = 0.f;

  const float* xbase = xin + ((size_t)n << 21);  // n*512*4096

  for (int c0 = 0; c0 < 512; c0 += 8) {
    __syncthreads();
    // stage weights: 72 rows x 64 o, coalesced from wt
    {
      const float4* g = (const float4*)(wt + (size_t)(c0 * 9) * 512);
      float4* s4 = (float4*)sW;
#pragma unroll
      for (int p = 0; p < 5; ++p) {
        int e4 = tid + (p << 8);
        if (e4 < 1152) {
          int r = e4 >> 4;
          int o = (e4 & 15) << 2;
          s4[e4] = g[(r * 512 + o0 + o) >> 2];
        }
      }
    }
    // stage input tile 8c x 18 x (18 valid of 20), zero-padded
#pragma unroll
    for (int p = 0; p < 12; ++p) {
      int e = tid + (p << 8);
      if (e < 2880) {
        int c = e / 360;
        int r = e - c * 360;
        int yy = r / 20;
        int xx = r - yy * 20;
        int gy = ty0 + yy - 1, gx = tx0 + xx - 1;
        float v = 0.f;
        if (xx < 18 && (unsigned)gy < 64u && (unsigned)gx < 64u)
          v = xbase[((c0 + c) << 12) + (gy << 6) + gx];
        sIn[e] = v;
      }
    }
    __syncthreads();

    for (int c = 0; c < 8; ++c) {
#pragma unroll
      for (int ky = 0; ky < 3; ++ky) {
        const float* rp = &sIn[(c * 18 + sy + ky) * 20 + x0l];
        float rin[10];
        float4 t0 = *(const float4*)rp;
        float4 t1 = *(const float4*)(rp + 4);
        float2 t2 = *(const float2*)(rp + 8);
        rin[0]=t0.x; rin[1]=t0.y; rin[2]=t0.z; rin[3]=t0.w;
        rin[4]=t1.x; rin[5]=t1.y; rin[6]=t1.z; rin[7]=t1.w;
        rin[8]=t2.x; rin[9]=t2.y;
#pragma unroll
        for (int kx = 0; kx < 3; ++kx) {
          const float4* wp = (const float4*)&sW[(c * 9 + ky * 3 + kx) * 64 + (ot << 3)];
          float4 wa = wp[0], wb = wp[1];
          float wr[8] = {wa.x, wa.y, wa.z, wa.w, wb.x, wb.y, wb.z, wb.w};
#pragma unroll
          for (int j = 0; j < 8; ++j)
#pragma unroll
            for (int d = 0; d < 8; ++d)
              acc[j][d] = fmaf(wr[j], rin[d + kx], acc[j][d]);
        }
      }
    }
  }

  const int oy = ty0 + sy, ox = tx0 + x0l;
#pragma unroll
  for (int j = 0; j < 8; ++j) {
    int o = o0 + (ot << 3) + j;
    float b = bias[o];
    float* dst = hout + (((size_t)(n * 512 + o)) << 12) + (oy << 6) + ox;
    float4 v0, v1;
    v0.x = fmaxf(acc[j][0] + b, 0.f); v0.y = fmaxf(acc[j][1] + b, 0.f);
    v0.z = fmaxf(acc[j][2] + b, 0.f); v0.w = fmaxf(acc[j][3] + b, 0.f);
    v1.x = fmaxf(acc[j][4] + b, 0.f); v1.y = fmaxf(acc[j][5] + b, 0.f);
    v1.z = fmaxf(acc[j][6] + b, 0.f); v1.w = fmaxf(acc[j][7] + b, 0.f);
    *(float4*)dst = v0;
    *(float4*)(dst + 4) = v1;
  }
}

// ---------------------------------------------------------------------------
// 2. 1x1 heads + softmax. grid (64 y, 2 n), block 256.
// Writes rpn_locs (O0), rpn_scores (O1), fg probs to ws.
// ---------------------------------------------------------------------------
__global__ __launch_bounds__(256) void head_kernel(
    const float* __restrict__ hbuf, const float* __restrict__ wslt,
    const float* __restrict__ wslb, float* __restrict__ out,
    float* __restrict__ fgbuf) {
  const int y = blockIdx.x, n = blockIdx.y;
  __shared__ float sH[1024];
  __shared__ float sWt[1024];
  __shared__ float sOut[64 * 65];
  const int tid = threadIdx.x;
  const int x = tid & 63, og = tid >> 6;  // og 0..3, o = og*16+j

  float acc[16];
#pragma unroll
  for (int j = 0; j < 16; ++j) acc[j] = 0.f;

  const float* hb = hbuf + ((size_t)n << 21) + (y << 6);

  for (int c0 = 0; c0 < 512; c0 += 16) {
    __syncthreads();
#pragma unroll
    for (int p = 0; p < 4; ++p) {
      int e = tid + (p << 8);
      int cc = e >> 6, xx = e & 63;
      sH[e] = hb[((size_t)(c0 + cc) << 12) + xx];
      sWt[e] = wslt[((c0 + cc) << 6) + xx];
    }
    __syncthreads();
#pragma unroll
    for (int cc = 0; cc < 16; ++cc) {
      float hv = sH[(cc << 6) + x];
      const float4* wp = (const float4*)&sWt[(cc << 6) + (og << 4)];
      float4 w0 = wp[0], w1 = wp[1], w2 = wp[2], w3 = wp[3];
      acc[0]  = fmaf(hv, w0.x, acc[0]);  acc[1]  = fmaf(hv, w0.y, acc[1]);
      acc[2]  = fmaf(hv, w0.z, acc[2]);  acc[3]  = fmaf(hv, w0.w, acc[3]);
      acc[4]  = fmaf(hv, w1.x, acc[4]);  acc[5]  = fmaf(hv, w1.y, acc[5]);
      acc[6]  = fmaf(hv, w1.z, acc[6]);  acc[7]  = fmaf(hv, w1.w, acc[7]);
      acc[8]  = fmaf(hv, w2.x, acc[8]);  acc[9]  = fmaf(hv, w2.y, acc[9]);
      acc[10] = fmaf(hv, w2.z, acc[10]); acc[11] = fmaf(hv, w2.w, acc[11]);
      acc[12] = fmaf(hv, w3.x, acc[12]); acc[13] = fmaf(hv, w3.y, acc[13]);
      acc[14] = fmaf(hv, w3.z, acc[14]); acc[15] = fmaf(hv, w3.w, acc[15]);
    }
  }
  __syncthreads();
#pragma unroll
  for (int j = 0; j < 16; ++j) {
    int o = (og << 4) + j;
    sOut[o * 65 + x] = acc[j] + wslb[o];
  }
  __syncthreads();

  const int p0 = (n << 12) + (y << 6);
  float* locs = out + O0 + (size_t)p0 * 36;
  for (int e = tid; e < 2304; e += 256) {
    int xx = e / 36, o = e - xx * 36;
    locs[e] = sOut[o * 65 + xx];
  }
  float* scrs = out + O1 + (size_t)p0 * 18;
  for (int e = tid; e < 1152; e += 256) {
    int xx = e / 18, s = e - xx * 18;
    scrs[e] = sOut[(36 + s) * 65 + xx];
  }
  float* fg = fgbuf + n * NANCH + (y << 6) * 9;
  for (int e = tid; e < 576; e += 256) {
    int xx = e / 9, a = e - xx * 9;
    float s0 = sOut[(36 + 2 * a) * 65 + xx];
    float s1 = sOut[(36 + 2 * a + 1) * 65 + xx];
    fg[e] = 1.0f / (1.0f + expf(s0 - s1));
  }
}

// ---------------------------------------------------------------------------
// 3. anchors + decode + clip + min-size + sort keys. grid 512, block 256.
// ---------------------------------------------------------------------------
__global__ __launch_bounds__(256) void decode_kernel(
    const float* __restrict__ out0, const float* __restrict__ fgbuf,
    float* __restrict__ scbuf, float4* __restrict__ roibuf,
    u64* __restrict__ keys, float* __restrict__ anchor_out,
    const int* __restrict__ imgh_p, const int* __restrict__ imgw_p) {
  int gid = blockIdx.x * 256 + threadIdx.x;   // < 131072
  int n = gid >> 16, k = gid & (SEG - 1);
  if (k >= NANCH) { keys[gid] = ~0ull; return; }
  int a = k % 9;
  int p = k / 9;
  int py = p >> 6, px = p & 63;

  // base anchors in f64 then cast (matches numpy)
  const double R[3] = {0.5, 1.0, 2.0};
  const double S[3] = {8.0, 16.0, 32.0};
  double r = R[a / 3], s = S[a - (a / 3) * 3];
  double hd = 16.0 * s * sqrt(r);
  double wd = 16.0 * s * sqrt(1.0 / r);
  float ay1 = (float)(8.0 - hd / 2.0) + (float)(py * 16);
  float ax1 = (float)(8.0 - wd / 2.0) + (float)(px * 16);
  float ay2 = (float)(8.0 + hd / 2.0) + (float)(py * 16);
  float ax2 = (float)(8.0 + wd / 2.0) + (float)(px * 16);
  if (n == 0) {
    float* ao = anchor_out + (size_t)k * 4;
    ao[0] = ay1; ao[1] = ax1; ao[2] = ay2; ao[3] = ax2;
  }
  float ahk = ay2 - ay1, awk = ax2 - ax1;
  float acy = ay1 + 0.5f * ahk, acx = ax1 + 0.5f * awk;
  const float* lp = out0 + ((size_t)(n * NANCH + k) << 2);
  float dy = lp[0], dx = lp[1], dh = lp[2], dw = lp[3];
  float cy = dy * ahk + acy;
  float cx = dx * awk + acx;
  float bh = expf(dh) * ahk;
  float bw = expf(dw) * awk;
  float img_h = (float)imgh_p[0], img_w = (float)imgw_p[0];
  float y1 = fminf(fmaxf(cy - 0.5f * bh, 0.f), img_h);
  float x1 = fminf(fmaxf(cx - 0.5f * bw, 0.f), img_w);
  float y2 = fminf(fmaxf(cy + 0.5f * bh, 0.f), img_h);
  float x2 = fminf(fmaxf(cx + 0.5f * bw, 0.f), img_w);
  bool valid = ((y2 - y1) >= 16.f) && ((x2 - x1) >= 16.f);
  float sc = valid ? fgbuf[n * NANCH + k] : -INFINITY;
  scbuf[n * NANCH + k] = sc;
  roibuf[n * NANCH + k] = make_float4(y1, x1, y2, x2);
  unsigned int b = __float_as_uint(sc);
  unsigned int m = b ^ ((b & 0x80000000u) ? 0xFFFFFFFFu : 0x80000000u);
  keys[gid] = ((u64)(~m) << 32) | (unsigned int)k;
}

// ---------------------------------------------------------------------------
// 4. init rois/roi_indices/vmask
// ---------------------------------------------------------------------------
__global__ __launch_bounds__(256) void init_out(float* __restrict__ out) {
  int e = blockIdx.x * 256 + threadIdx.x;
  if (e < 2400) out[O2 + e] = 0.f;
  else if (e < 3000) out[O3 + (e - 2400)] = (float)((e - 2400) / 300);
  else if (e < 3600) out[O5 + (e - 3000)] = 0.f;
}

// ---------------------------------------------------------------------------
// 5. bitonic sort of 2 x 65536 u64 keys (ascending per segment)
// ---------------------------------------------------------------------------
__global__ __launch_bounds__(256) void sort_local_a(u64* __restrict__ keys) {
  __shared__ u64 sk[2048];
  const int base = blockIdx.x << 11;
  for (int e = threadIdx.x; e < 2048; e += 256) sk[e] = keys[base + e];
  __syncthreads();
  for (int k = 2; k <= 2048; k <<= 1) {
    for (int j = k >> 1; j > 0; j >>= 1) {
      for (int t = threadIdx.x; t < 1024; t += 256) {
        int l = ((t & ~(j - 1)) << 1) | (t & (j - 1));
        int rr = l | j;
        bool asc = ((((base + l) & (SEG - 1)) & k) == 0);
        u64 a = sk[l], b = sk[rr];
        if ((a > b) == asc) { sk[l] = b; sk[rr] = a; }
      }
      __syncthreads();
    }
  }
  for (int e = threadIdx.x; e < 2048; e += 256) keys[base + e] = sk[e];
}

__global__ __launch_bounds__(256) void sort_global_pass(u64* __restrict__ keys,
                                                        int k, int j) {
  int t = blockIdx.x * 256 + threadIdx.x;   // 0..65535
  int l = ((t & ~(j - 1)) << 1) | (t & (j - 1));
  int rr = l | j;
  bool asc = (((l & (SEG - 1)) & k) == 0);
  u64 a = keys[l], b = keys[rr];
  if ((a > b) == asc) { keys[l] = b; keys[rr] = a; }
}

__global__ __launch_bounds__(256) void sort_local_b(u64* __restrict__ keys, int k) {
  __shared__ u64 sk[2048];
  const int base = blockIdx.x << 11;
  for (int e = threadIdx.x; e < 2048; e += 256) sk[e] = keys[base + e];
  __syncthreads();
  for (int j = 1024; j > 0; j >>= 1) {
    for (int t = threadIdx.x; t < 1024; t += 256) {
      int l = ((t & ~(j - 1)) << 1) | (t & (j - 1));
      int rr = l | j;
      bool asc = ((((base + l) & (SEG - 1)) & k) == 0);
      u64 a = sk[l], b = sk[rr];
      if ((a > b) == asc) { sk[l] = b; sk[rr] = a; }
    }
    __syncthreads();
  }
  for (int e = threadIdx.x; e < 2048; e += 256) keys[base + e] = sk[e];
}

// ---------------------------------------------------------------------------
// 6. greedy NMS, one wave per image (wave-synchronous)
// ---------------------------------------------------------------------------
__global__ __launch_bounds__(64) void nms_kernel(
    const u64* __restrict__ keys, const float4* __restrict__ roibuf,
    const float* __restrict__ scbuf, float* __restrict__ out) {
  const int n = blockIdx.x;
  const int lane = threadIdx.x;
  __shared__ float4 kb[N_POST];
  int nk = 0;
  float* rois = out + O2 + n * (N_POST * 4);
  float* vmask = out + O5 + n * N_POST;
  const u64* kseg = keys + ((size_t)n << 16);
  const float4* rseg = roibuf + (size_t)n * NANCH;
  const float* sseg = scbuf + (size_t)n * NANCH;

  for (int i = 0; i < N_PRE; ++i) {
    u64 kk = kseg[i];
    unsigned int idx = (unsigned int)(kk & 0xFFFFFFFFull);
    float sc = sseg[idx];
    if (!(sc >= -3.0e38f)) break;   // -inf (or NaN): all that follow too
    float4 cur = rseg[idx];
    float areaC = (cur.z - cur.x) * (cur.w - cur.y);
    bool sup = false;
    for (int j = lane; j < nk; j += 64) {
      float4 b = kb[j];
      float areaB = (b.z - b.x) * (b.w - b.y);
      float ih = fmaxf(fminf(cur.z, b.z) - fmaxf(cur.x, b.x), 0.f);
      float iw = fmaxf(fminf(cur.w, b.w) - fmaxf(cur.y, b.y), 0.f);
      float inter = ih * iw;
      float iou = inter / (areaC + areaB - inter + 1e-9f);
      if (iou > 0.7f) sup = true;
    }
    if (!__any(sup)) {
      if (lane == 0) {
        kb[nk] = cur;
        rois[nk * 4 + 0] = cur.x;
        rois[nk * 4 + 1] = cur.y;
        rois[nk * 4 + 2] = cur.z;
        rois[nk * 4 + 3] = cur.w;
        vmask[nk] = 1.0f;
      }
      __syncthreads();  // single wave: cheap; guarantees kb visibility/order
      ++nk;
      if (nk >= N_POST) break;
    }
  }
}

// ---------------------------------------------------------------------------
extern "C" void kernel_launch(void* const* d_in, const int* in_sizes, int n_in,
                              void* d_out, int out_size, void* d_ws, size_t ws_size,
                              hipStream_t stream) {
  const float* x        = (const float*)d_in[0];
  const float* conv1_w  = (const float*)d_in[1];
  const float* conv1_b  = (const float*)d_in[2];
  const float* score_w  = (const float*)d_in[3];
  const float* score_b  = (const float*)d_in[4];
  const float* loc_w    = (const float*)d_in[5];
  const float* loc_b    = (const float*)d_in[6];
  const int*   imgh_p   = (const int*)d_in[7];
  const int*   imgw_p   = (const int*)d_in[8];

  float* out = (float*)d_out;
  float* ws  = (float*)d_ws;

  float* wt    = ws + WS_WT;
  float* wslt  = ws + WS_WSLT;
  float* wslb  = ws + WS_WSLB;
  float* hbuf  = ws + WS_H;
  float* fgbuf = ws + WS_FG;
  float* scbuf = ws + WS_SC;
  float4* roibuf = (float4*)(ws + WS_ROI);
  u64* keys    = (u64*)(ws + WS_KEYS);

  prep_weights<<<9345, 256, 0, stream>>>(conv1_w, loc_w, score_w, loc_b,
                                         score_b, wt, wslt, wslb);
  conv3x3<<<dim3(16, 8, 2), 256, 0, stream>>>(x, wt, conv1_b, hbuf);
  head_kernel<<<dim3(64, 2), 256, 0, stream>>>(hbuf, wslt, wslb, out, fgbuf);
  decode_kernel<<<512, 256, 0, stream>>>(out, fgbuf, scbuf, roibuf, keys,
                                         out + O4, imgh_p, imgw_p);
  init_out<<<15, 256, 0, stream>>>(out);

  sort_local_a<<<64, 256, 0, stream>>>(keys);
  for (int k = 4096; k <= SEG; k <<= 1) {
    for (int j = k >> 1; j >= 2048; j >>= 1)
      sort_global_pass<<<256, 256, 0, stream>>>(keys, k, j);
    sort_local_b<<<64, 256, 0, stream>>>(keys, k);
  }

  nms_kernel<<<2, 64, 0, stream>>>(keys, roibuf, scbuf, out);
}

// Round 2
// 1157.765 us; speedup vs baseline: 1.1401x; 1.1401x over previous
//
#include <hip/hip_runtime.h>
#include <hip/hip_bf16.h>
#include <math.h>
#include <cstdint>

typedef unsigned long long u64;

// ---------------------------------------------------------------------------
// Sizes
// ---------------------------------------------------------------------------
#define HH 64
#define WW 64
#define NPIX 4096          // 64*64
#define NANCH 36864        // 4096*9
#define SEG 65536          // padded per-image sort segment
#define N_PRE 6000
#define N_POST 300

// output float offsets
#define O0 0               // rpn_locs  2*36864*4 = 294912
#define O1 294912          // rpn_scores 2*36864*2 = 147456
#define O2 442368          // rois 2*300*4 = 2400
#define O3 444768          // roi_indices 600
#define O4 445368          // anchor 147456
#define O5 592824          // vmask 600

// workspace float offsets
#define WS_WT 0                       // 2359296  (w transposed [c*9+t][512])
#define WS_WSLT 2359296               // 32768    ([c][64] loc(36)+score(18)+pad)
#define WS_WSLB (WS_WSLT + 32768)     // 64
#define WS_H (WS_WSLB + 64)           // 4194304  h buffer (pre-bias, pre-relu)
#define WS_FG (WS_H + 4194304)        // 73728
#define WS_SC (WS_FG + 73728)         // 73728 (unused now, kept for layout)
#define WS_ROI (WS_SC + 73728)        // 294912 (float4 aligned)
#define WS_KEYS (WS_ROI + 294912)     // 131072 u64

// ---------------------------------------------------------------------------
// 0a. zero hbuf (atomic accumulation target)
// ---------------------------------------------------------------------------
__global__ __launch_bounds__(256) void zero_h(float4* __restrict__ h) {
  h[blockIdx.x * 256 + threadIdx.x] = make_float4(0.f, 0.f, 0.f, 0.f);
}

// ---------------------------------------------------------------------------
// 0b. conv weight transpose [o][c*9+t] -> [c*9+t][o], coalesced via LDS tile
// ---------------------------------------------------------------------------
__global__ __launch_bounds__(256) void prep_wt(const float* __restrict__ w,
                                               float* __restrict__ wt) {
  __shared__ float s[64 * 65];
  const int r0 = blockIdx.x << 6;   // 72 row tiles
  const int o0 = blockIdx.y << 6;   // 8 o tiles
  const int tid = threadIdx.x;
#pragma unroll
  for (int p = 0; p < 16; ++p) {
    int idx = (p << 8) + tid;
    int ol = idx >> 6, rl = idx & 63;
    s[ol * 65 + rl] = w[(size_t)(o0 + ol) * 4608 + r0 + rl];  // coalesced in rl
  }
  __syncthreads();
#pragma unroll
  for (int p = 0; p < 16; ++p) {
    int idx = (p << 8) + tid;
    int rl = idx >> 6, ol = idx & 63;
    wt[(size_t)(r0 + rl) * 512 + o0 + ol] = s[ol * 65 + rl]; // coalesced in ol
  }
}

// ---------------------------------------------------------------------------
// 0c. pack 1x1 head weights + biases (small)
// ---------------------------------------------------------------------------
__global__ __launch_bounds__(256) void prep_small(
    const float* __restrict__ lw, const float* __restrict__ sw,
    const float* __restrict__ lb, const float* __restrict__ sb,
    float* __restrict__ wslt, float* __restrict__ wslb) {
  int e = blockIdx.x * 256 + threadIdx.x;
  if (e < 32768) {
    int c = e >> 6, o = e & 63;
    float v = 0.f;
    if (o < 36) v = lw[o * 512 + c];
    else if (o < 54) v = sw[(o - 36) * 512 + c];
    wslt[e] = v;
  } else if (e < 32832) {
    int o = e - 32768;
    float v = 0.f;
    if (o < 36) v = lb[o];
    else if (o < 54) v = sb[o - 36];
    wslb[o] = v;
  }
}

// ---------------------------------------------------------------------------
// 1. 3x3 conv 512->512 SAME, K-split x4 for occupancy.
// grid (16 spatial tiles, 8 o-groups, 2n x 4q), block 256.
// Block: 64 o x (16x16) spatial over 128 channels; partial sums atomicAdd'd
// into zeroed hbuf. Bias+ReLU applied by head_kernel at load.
// R1: 256 blocks -> 1 blk/CU -> VALUBusy 40%. 1024 blocks -> 4 blk/CU.
// ---------------------------------------------------------------------------
__global__ __launch_bounds__(256) void conv3x3(
    const float* __restrict__ xin, const float* __restrict__ wt,
    float* __restrict__ hout) {
  __shared__ float sIn[2880];   // [8c][18y][20x]
  __shared__ float sW[4608];    // [72][64]
  const int tid = threadIdx.x;
  const int tile = blockIdx.x, og = blockIdx.y, z = blockIdx.z;
  const int n = z >> 2, q = z & 3;
  const int ty0 = (tile >> 2) << 4, tx0 = (tile & 3) << 4;
  const int o0 = og << 6;
  const int ot = tid >> 5;          // 0..7
  const int st = tid & 31;
  const int sy = st >> 1;           // 0..15
  const int x0l = (st & 1) << 3;    // 0 or 8

  float acc[8][8];
#pragma unroll
  for (int j = 0; j < 8; ++j)
#pragma unroll
    for (int d = 0; d < 8; ++d) acc[j][d] = 0.f;

  const float* xbase = xin + ((size_t)n << 21);  // n*512*4096
  const int cbeg = q << 7;                       // 128-channel slice

  for (int c0 = cbeg; c0 < cbeg + 128; c0 += 8) {
    __syncthreads();
    // stage weights: 72 rows x 64 o, coalesced from wt
    {
      const float4* g = (const float4*)(wt + (size_t)(c0 * 9) * 512);
      float4* s4 = (float4*)sW;
#pragma unroll
      for (int p = 0; p < 5; ++p) {
        int e4 = tid + (p << 8);
        if (e4 < 1152) {
          int r = e4 >> 4;
          int o = (e4 & 15) << 2;
          s4[e4] = g[(r * 512 + o0 + o) >> 2];
        }
      }
    }
    // stage input tile 8c x 18 x (18 valid of 20), zero-padded
#pragma unroll
    for (int p = 0; p < 12; ++p) {
      int e = tid + (p << 8);
      if (e < 2880) {
        int c = e / 360;
        int r = e - c * 360;
        int yy = r / 20;
        int xx = r - yy * 20;
        int gy = ty0 + yy - 1, gx = tx0 + xx - 1;
        float v = 0.f;
        if (xx < 18 && (unsigned)gy < 64u && (unsigned)gx < 64u)
          v = xbase[((c0 + c) << 12) + (gy << 6) + gx];
        sIn[e] = v;
      }
    }
    __syncthreads();

    for (int c = 0; c < 8; ++c) {
#pragma unroll
      for (int ky = 0; ky < 3; ++ky) {
        const float* rp = &sIn[(c * 18 + sy + ky) * 20 + x0l];
        float rin[10];
        float4 t0 = *(const float4*)rp;
        float4 t1 = *(const float4*)(rp + 4);
        float2 t2 = *(const float2*)(rp + 8);
        rin[0]=t0.x; rin[1]=t0.y; rin[2]=t0.z; rin[3]=t0.w;
        rin[4]=t1.x; rin[5]=t1.y; rin[6]=t1.z; rin[7]=t1.w;
        rin[8]=t2.x; rin[9]=t2.y;
#pragma unroll
        for (int kx = 0; kx < 3; ++kx) {
          const float4* wp = (const float4*)&sW[(c * 9 + ky * 3 + kx) * 64 + (ot << 3)];
          float4 wa = wp[0], wb = wp[1];
          float wr[8] = {wa.x, wa.y, wa.z, wa.w, wb.x, wb.y, wb.z, wb.w};
#pragma unroll
          for (int j = 0; j < 8; ++j)
#pragma unroll
            for (int d = 0; d < 8; ++d)
              acc[j][d] = fmaf(wr[j], rin[d + kx], acc[j][d]);
        }
      }
    }
  }

  const int oy = ty0 + sy, ox = tx0 + x0l;
#pragma unroll
  for (int j = 0; j < 8; ++j) {
    int o = o0 + (ot << 3) + j;
    float* dst = hout + (((size_t)(n * 512 + o)) << 12) + (oy << 6) + ox;
#pragma unroll
    for (int d = 0; d < 8; ++d) atomicAdd(dst + d, acc[j][d]);
  }
}

// ---------------------------------------------------------------------------
// 2. 1x1 heads + softmax. grid (64 y, 2 n), block 256.
// Applies bias+ReLU to hbuf at staging (conv writes raw partial sums).
// ---------------------------------------------------------------------------
__global__ __launch_bounds__(256) void head_kernel(
    const float* __restrict__ hbuf, const float* __restrict__ cb,
    const float* __restrict__ wslt, const float* __restrict__ wslb,
    float* __restrict__ out, float* __restrict__ fgbuf) {
  const int y = blockIdx.x, n = blockIdx.y;
  __shared__ float sH[1024];
  __shared__ float sWt[1024];
  __shared__ float sOut[64 * 65];
  const int tid = threadIdx.x;
  const int x = tid & 63, og = tid >> 6;  // og 0..3, o = og*16+j

  float acc[16];
#pragma unroll
  for (int j = 0; j < 16; ++j) acc[j] = 0.f;

  const float* hb = hbuf + ((size_t)n << 21) + (y << 6);

  for (int c0 = 0; c0 < 512; c0 += 16) {
    __syncthreads();
#pragma unroll
    for (int p = 0; p < 4; ++p) {
      int e = tid + (p << 8);
      int cc = e >> 6, xx = e & 63;
      sH[e] = fmaxf(hb[((size_t)(c0 + cc) << 12) + xx] + cb[c0 + cc], 0.f);
      sWt[e] = wslt[((c0 + cc) << 6) + xx];
    }
    __syncthreads();
#pragma unroll
    for (int cc = 0; cc < 16; ++cc) {
      float hv = sH[(cc << 6) + x];
      const float4* wp = (const float4*)&sWt[(cc << 6) + (og << 4)];
      float4 w0 = wp[0], w1 = wp[1], w2 = wp[2], w3 = wp[3];
      acc[0]  = fmaf(hv, w0.x, acc[0]);  acc[1]  = fmaf(hv, w0.y, acc[1]);
      acc[2]  = fmaf(hv, w0.z, acc[2]);  acc[3]  = fmaf(hv, w0.w, acc[3]);
      acc[4]  = fmaf(hv, w1.x, acc[4]);  acc[5]  = fmaf(hv, w1.y, acc[5]);
      acc[6]  = fmaf(hv, w1.z, acc[6]);  acc[7]  = fmaf(hv, w1.w, acc[7]);
      acc[8]  = fmaf(hv, w2.x, acc[8]);  acc[9]  = fmaf(hv, w2.y, acc[9]);
      acc[10] = fmaf(hv, w2.z, acc[10]); acc[11] = fmaf(hv, w2.w, acc[11]);
      acc[12] = fmaf(hv, w3.x, acc[12]); acc[13] = fmaf(hv, w3.y, acc[13]);
      acc[14] = fmaf(hv, w3.z, acc[14]); acc[15] = fmaf(hv, w3.w, acc[15]);
    }
  }
  __syncthreads();
#pragma unroll
  for (int j = 0; j < 16; ++j) {
    int o = (og << 4) + j;
    sOut[o * 65 + x] = acc[j] + wslb[o];
  }
  __syncthreads();

  const int p0 = (n << 12) + (y << 6);
  float* locs = out + O0 + (size_t)p0 * 36;
  for (int e = tid; e < 2304; e += 256) {
    int xx = e / 36, o = e - xx * 36;
    locs[e] = sOut[o * 65 + xx];
  }
  float* scrs = out + O1 + (size_t)p0 * 18;
  for (int e = tid; e < 1152; e += 256) {
    int xx = e / 18, s = e - xx * 18;
    scrs[e] = sOut[(36 + s) * 65 + xx];
  }
  float* fg = fgbuf + n * NANCH + (y << 6) * 9;
  for (int e = tid; e < 576; e += 256) {
    int xx = e / 9, a = e - xx * 9;
    float s0 = sOut[(36 + 2 * a) * 65 + xx];
    float s1 = sOut[(36 + 2 * a + 1) * 65 + xx];
    fg[e] = 1.0f / (1.0f + expf(s0 - s1));
  }
}

// ---------------------------------------------------------------------------
// 3. anchors + decode + clip + min-size + sort keys. grid 512, block 256.
// ---------------------------------------------------------------------------
__global__ __launch_bounds__(256) void decode_kernel(
    const float* __restrict__ out0, const float* __restrict__ fgbuf,
    float4* __restrict__ roibuf, u64* __restrict__ keys,
    float* __restrict__ anchor_out,
    const int* __restrict__ imgh_p, const int* __restrict__ imgw_p) {
  int gid = blockIdx.x * 256 + threadIdx.x;   // < 131072
  int n = gid >> 16, k = gid & (SEG - 1);
  if (k >= NANCH) { keys[gid] = ~0ull; return; }
  int a = k % 9;
  int p = k / 9;
  int py = p >> 6, px = p & 63;

  // base anchors in f64 then cast (matches numpy)
  const double R[3] = {0.5, 1.0, 2.0};
  const double S[3] = {8.0, 16.0, 32.0};
  double r = R[a / 3], s = S[a - (a / 3) * 3];
  double hd = 16.0 * s * sqrt(r);
  double wd = 16.0 * s * sqrt(1.0 / r);
  float ay1 = (float)(8.0 - hd / 2.0) + (float)(py * 16);
  float ax1 = (float)(8.0 - wd / 2.0) + (float)(px * 16);
  float ay2 = (float)(8.0 + hd / 2.0) + (float)(py * 16);
  float ax2 = (float)(8.0 + wd / 2.0) + (float)(px * 16);
  if (n == 0) {
    float* ao = anchor_out + (size_t)k * 4;
    ao[0] = ay1; ao[1] = ax1; ao[2] = ay2; ao[3] = ax2;
  }
  float ahk = ay2 - ay1, awk = ax2 - ax1;
  float acy = ay1 + 0.5f * ahk, acx = ax1 + 0.5f * awk;
  const float* lp = out0 + ((size_t)(n * NANCH + k) << 2);
  float dy = lp[0], dx = lp[1], dh = lp[2], dw = lp[3];
  float cy = dy * ahk + acy;
  float cx = dx * awk + acx;
  float bh = expf(dh) * ahk;
  float bw = expf(dw) * awk;
  float img_h = (float)imgh_p[0], img_w = (float)imgw_p[0];
  float y1 = fminf(fmaxf(cy - 0.5f * bh, 0.f), img_h);
  float x1 = fminf(fmaxf(cx - 0.5f * bw, 0.f), img_w);
  float y2 = fminf(fmaxf(cy + 0.5f * bh, 0.f), img_h);
  float x2 = fminf(fmaxf(cx + 0.5f * bw, 0.f), img_w);
  bool valid = ((y2 - y1) >= 16.f) && ((x2 - x1) >= 16.f);
  float sc = valid ? fgbuf[n * NANCH + k] : -INFINITY;
  roibuf[n * NANCH + k] = make_float4(y1, x1, y2, x2);
  unsigned int b = __float_as_uint(sc);
  unsigned int m = b ^ ((b & 0x80000000u) ? 0xFFFFFFFFu : 0x80000000u);
  keys[gid] = ((u64)(~m) << 32) | (unsigned int)k;  // -inf -> hi = 0xFF800000
}

// ---------------------------------------------------------------------------
// 4. init rois/roi_indices/vmask
// ---------------------------------------------------------------------------
__global__ __launch_bounds__(256) void init_out(float* __restrict__ out) {
  int e = blockIdx.x * 256 + threadIdx.x;
  if (e < 2400) out[O2 + e] = 0.f;
  else if (e < 3000) out[O3 + (e - 2400)] = (float)((e - 2400) / 300);
  else if (e < 3600) out[O5 + (e - 3000)] = 0.f;
}

// ---------------------------------------------------------------------------
// 5. bitonic sort, 4096-span local kernels + fused double-step global passes.
// 21 launches (R1) -> 11.
// ---------------------------------------------------------------------------
__global__ __launch_bounds__(256) void sort_local_a(u64* __restrict__ keys) {
  __shared__ u64 sk[4096];
  const int base = blockIdx.x << 12;
  for (int e = threadIdx.x; e < 4096; e += 256) sk[e] = keys[base + e];
  __syncthreads();
  for (int k = 2; k <= 4096; k <<= 1) {
    for (int j = k >> 1; j > 0; j >>= 1) {
      for (int t = threadIdx.x; t < 2048; t += 256) {
        int l = ((t & ~(j - 1)) << 1) | (t & (j - 1));
        int rr = l | j;
        bool asc = (((base + l) & k) == 0);
        u64 a = sk[l], b = sk[rr];
        if ((a > b) == asc) { sk[l] = b; sk[rr] = a; }
      }
      __syncthreads();
    }
  }
  for (int e = threadIdx.x; e < 4096; e += 256) keys[base + e] = sk[e];
}

// one j-step, j >= 4096
__global__ __launch_bounds__(256) void sort_global_pass(u64* __restrict__ keys,
                                                        int k, int j) {
  int t = blockIdx.x * 256 + threadIdx.x;   // 0..65535
  int l = ((t & ~(j - 1)) << 1) | (t & (j - 1));
  int rr = l | j;
  bool asc = (((l & (SEG - 1)) & k) == 0);
  u64 a = keys[l], b = keys[rr];
  if ((a > b) == asc) { keys[l] = b; keys[rr] = a; }
}

// two j-steps fused (j1 then j1/2), both >= 4096
__global__ __launch_bounds__(256) void sort_global_pass2(u64* __restrict__ keys,
                                                         int k, int j1) {
  int t = blockIdx.x * 256 + threadIdx.x;   // 0..32767
  int j2 = j1 >> 1;
  int l = ((t & ~(j2 - 1)) << 1) | (t & (j2 - 1));
  l = ((l & ~(j1 - 1)) << 1) | (l & (j1 - 1));
  u64 e0 = keys[l], e1 = keys[l | j2], e2 = keys[l | j1], e3 = keys[l | j1 | j2];
  bool asc = (((l & (SEG - 1)) & k) == 0);
  u64 tmp;
  if ((e0 > e2) == asc) { tmp = e0; e0 = e2; e2 = tmp; }
  if ((e1 > e3) == asc) { tmp = e1; e1 = e3; e3 = tmp; }
  if ((e0 > e1) == asc) { tmp = e0; e0 = e1; e1 = tmp; }
  if ((e2 > e3) == asc) { tmp = e2; e2 = e3; e3 = tmp; }
  keys[l] = e0; keys[l | j2] = e1; keys[l | j1] = e2; keys[l | j1 | j2] = e3;
}

__global__ __launch_bounds__(256) void sort_local_b(u64* __restrict__ keys, int k) {
  __shared__ u64 sk[4096];
  const int base = blockIdx.x << 12;
  for (int e = threadIdx.x; e < 4096; e += 256) sk[e] = keys[base + e];
  __syncthreads();
  for (int j = 2048; j > 0; j >>= 1) {
    for (int t = threadIdx.x; t < 2048; t += 256) {
      int l = ((t & ~(j - 1)) << 1) | (t & (j - 1));
      int rr = l | j;
      bool asc = ((((base + l) & (SEG - 1)) & k) == 0);
      u64 a = sk[l], b = sk[rr];
      if ((a > b) == asc) { sk[l] = b; sk[rr] = a; }
    }
    __syncthreads();
  }
  for (int e = threadIdx.x; e < 4096; e += 256) keys[base + e] = sk[e];
}

// ---------------------------------------------------------------------------
// 6. chunked greedy NMS, one wave per image.
// R1 version: serial per-candidate with dependent global loads (~250 cyc/iter).
// Now: 64 candidates/chunk; in-register pairwise matrix (shfl) + 64-step
// in-register resolve; kept-list check is throughput-bound LDS scan.
// ---------------------------------------------------------------------------
__global__ __launch_bounds__(64) void nms_kernel(
    const u64* __restrict__ keys, const float4* __restrict__ roibuf,
    float* __restrict__ out) {
  const int n = blockIdx.x;
  const int lane = threadIdx.x;
  __shared__ float kb_y1[N_POST], kb_x1[N_POST], kb_y2[N_POST], kb_x2[N_POST],
      kb_a[N_POST];
  float* rois = out + O2 + n * (N_POST * 4);
  float* vmask = out + O5 + n * N_POST;
  const u64* kseg = keys + ((size_t)n << 16);
  const float4* rseg = roibuf + (size_t)n * NANCH;
  int nk = 0;

  for (int c0 = 0; c0 < N_PRE && nk < N_POST; c0 += 64) {
    int i = c0 + lane;
    u64 kk = (i < N_PRE) ? kseg[i] : ~0ull;
    bool valid = ((unsigned)(kk >> 32)) < 0xFF800000u;  // score > -inf
    float4 bx = make_float4(0.f, 0.f, 0.f, 0.f);
    if (valid) bx = rseg[(unsigned)(kk & 0xFFFFFFFFu)];
    float area = (bx.z - bx.x) * (bx.w - bx.y);

    // suppressed by already-kept boxes? (LDS broadcast scan)
    bool sup = false;
    for (int j = 0; j < nk && !sup; ++j) {
      float ih = fmaxf(fminf(bx.z, kb_y2[j]) - fmaxf(bx.x, kb_y1[j]), 0.f);
      float iw = fmaxf(fminf(bx.w, kb_x2[j]) - fmaxf(bx.y, kb_x1[j]), 0.f);
      float inter = ih * iw;
      sup = inter / (area + kb_a[j] - inter + 1e-9f) > 0.7f;
    }
    u64 alive = __ballot(valid) & ~__ballot(sup);

    // pairwise suppression matrix within chunk (column mask per lane)
    u64 supmask = 0;
    for (int j = 0; j < 64; ++j) {
      float jy1 = __shfl(bx.x, j), jx1 = __shfl(bx.y, j);
      float jy2 = __shfl(bx.z, j), jx2 = __shfl(bx.w, j);
      float ja = __shfl(area, j);
      float ih = fmaxf(fminf(bx.z, jy2) - fmaxf(bx.x, jy1), 0.f);
      float iw = fmaxf(fminf(bx.w, jx2) - fmaxf(bx.y, jx1), 0.f);
      float inter = ih * iw;
      bool bit = (inter / (area + ja - inter + 1e-9f) > 0.7f) && (j < lane);
      supmask |= ((u64)bit) << j;
    }

    // serial in-register resolve (all lanes replicate the same kept set)
    u64 kept = 0;
    for (int j = 0; j < 64; ++j) {
      u64 smj = __shfl(supmask, j);
      bool kj = ((alive >> j) & 1ull) && ((smj & kept) == 0ull);
      kept |= ((u64)kj) << j;
    }

    // append kept boxes
    u64 below = (lane == 0) ? 0ull : (~0ull >> (64 - lane));
    int rank = __popcll(kept & below);
    if ((kept >> lane) & 1ull) {
      int slot = nk + rank;
      if (slot < N_POST) {
        kb_y1[slot] = bx.x; kb_x1[slot] = bx.y;
        kb_y2[slot] = bx.z; kb_x2[slot] = bx.w; kb_a[slot] = area;
        rois[slot * 4 + 0] = bx.x; rois[slot * 4 + 1] = bx.y;
        rois[slot * 4 + 2] = bx.z; rois[slot * 4 + 3] = bx.w;
        vmask[slot] = 1.0f;
      }
    }
    nk += __popcll(kept);
    if (nk > N_POST) nk = N_POST;
    __syncthreads();
    if (__ballot(valid) == 0) break;  // sorted: all-invalid chunk ends stream
  }
}

// ---------------------------------------------------------------------------
extern "C" void kernel_launch(void* const* d_in, const int* in_sizes, int n_in,
                              void* d_out, int out_size, void* d_ws, size_t ws_size,
                              hipStream_t stream) {
  const float* x        = (const float*)d_in[0];
  const float* conv1_w  = (const float*)d_in[1];
  const float* conv1_b  = (const float*)d_in[2];
  const float* score_w  = (const float*)d_in[3];
  const float* score_b  = (const float*)d_in[4];
  const float* loc_w    = (const float*)d_in[5];
  const float* loc_b    = (const float*)d_in[6];
  const int*   imgh_p   = (const int*)d_in[7];
  const int*   imgw_p   = (const int*)d_in[8];

  float* out = (float*)d_out;
  float* ws  = (float*)d_ws;

  float* wt    = ws + WS_WT;
  float* wslt  = ws + WS_WSLT;
  float* wslb  = ws + WS_WSLB;
  float* hbuf  = ws + WS_H;
  float* fgbuf = ws + WS_FG;
  float4* roibuf = (float4*)(ws + WS_ROI);
  u64* keys    = (u64*)(ws + WS_KEYS);

  zero_h<<<4096, 256, 0, stream>>>((float4*)hbuf);
  prep_wt<<<dim3(72, 8), 256, 0, stream>>>(conv1_w, wt);
  prep_small<<<129, 256, 0, stream>>>(loc_w, score_w, loc_b, score_b, wslt, wslb);
  conv3x3<<<dim3(16, 8, 8), 256, 0, stream>>>(x, wt, hbuf);
  head_kernel<<<dim3(64, 2), 256, 0, stream>>>(hbuf, conv1_b, wslt, wslb, out, fgbuf);
  decode_kernel<<<512, 256, 0, stream>>>(out, fgbuf, roibuf, keys,
                                         out + O4, imgh_p, imgw_p);
  init_out<<<15, 256, 0, stream>>>(out);

  sort_local_a<<<32, 256, 0, stream>>>(keys);
  for (int k = 8192; k <= SEG; k <<= 1) {
    int j = k >> 1;
    while (j >= 4096) {
      if (j >= 8192) {
        sort_global_pass2<<<128, 256, 0, stream>>>(keys, k, j);
        j >>= 2;
      } else {
        sort_global_pass<<<256, 256, 0, stream>>>(keys, k, j);
        j >>= 1;
      }
    }
    sort_local_b<<<32, 256, 0, stream>>>(keys, k);
  }

  nms_kernel<<<2, 64, 0, stream>>>(keys, roibuf, out);
}

// Round 3
// 554.615 us; speedup vs baseline: 2.3800x; 2.0875x over previous
//
#include <hip/hip_runtime.h>
#include <hip/hip_bf16.h>
#include <math.h>
#include <cstdint>

typedef unsigned long long u64;
typedef unsigned int u32;
typedef _Float16 half8 __attribute__((ext_vector_type(8)));
typedef float floatx4 __attribute__((ext_vector_type(4)));

// ---------------------------------------------------------------------------
// Sizes
// ---------------------------------------------------------------------------
#define NANCH 36864        // 4096*9
#define SEG 65536          // padded per-image sort segment
#define N_PRE 6000
#define N_POST 300

// output float offsets
#define O0 0               // rpn_locs  2*36864*4 = 294912
#define O1 294912          // rpn_scores 2*36864*2 = 147456
#define O2 442368          // rois 2*300*4 = 2400
#define O3 444768          // roi_indices 600
#define O4 445368          // anchor 147456
#define O5 592824          // vmask 600

// workspace float offsets
#define WS_XHI   0                        // xhi f16 [2][4096][512] = 4,194,304 f16 (2,097,152 f)
#define WS_XLO   2097152
#define WS_WHI   4194304                  // whi f16 [9][512][512] (1,179,648 f)
#define WS_WLO   5373952
#define WS_WSLT  6553600                  // 32768
#define WS_WSLB  6586368                  // 64
#define WS_H     6586432                  // hbuf f32 [2][4096][512] = 4,194,304 f
#define WS_GUARD 10780736                 // 64 floats of zeros (OOB target)
// overlays into dead XHI region (used only after conv completes):
#define WS_FG    0                        // 73728
#define WS_ROI   73728                    // 294912 (16B aligned)
#define WS_KEYS  368640                   // 131072 u64 = 262144 f

#define HSCALE 9.5367431640625e-07f       // 2^-20 (undo the 2^10 x 2^10 input scaling)

// ---------------------------------------------------------------------------
// async global->LDS, 16B per lane. LDS dest = wave-uniform base + lane*16.
// ---------------------------------------------------------------------------
__device__ __forceinline__ void gl_lds16(const void* g, void* l) {
  __builtin_amdgcn_global_load_lds(
      (const __attribute__((address_space(1))) u32*)g,
      (__attribute__((address_space(3))) u32*)l, 16, 0, 0);
}

// ---------------------------------------------------------------------------
// 0a. zero hbuf (atomic accumulation target) + guard page
// ---------------------------------------------------------------------------
__global__ __launch_bounds__(256) void zero_h(float4* __restrict__ h,
                                              float4* __restrict__ guard) {
  int idx = blockIdx.x * 256 + threadIdx.x;
  if (idx < 1048576) h[idx] = make_float4(0.f, 0.f, 0.f, 0.f);
  else if (idx < 1048576 + 16) guard[idx - 1048576] = make_float4(0.f, 0.f, 0.f, 0.f);
}

// ---------------------------------------------------------------------------
// 0b. x convert: [n][c][pix] f32 -> [n][pix][c] f16 hi/lo, scaled x1024.
// ---------------------------------------------------------------------------
__global__ __launch_bounds__(256) void xcvt(const float* __restrict__ x,
                                            _Float16* __restrict__ xhi,
                                            _Float16* __restrict__ xlo) {
  __shared__ float s[64 * 65];
  const int pt = blockIdx.x, cg = blockIdx.y, n = blockIdx.z;
  const int c0 = cg << 6, p0 = pt << 6;
  const int tid = threadIdx.x;
#pragma unroll
  for (int kk = 0; kk < 16; ++kk) {
    int e = tid + (kk << 8);
    int ci = e >> 6, pi = e & 63;
    s[ci * 65 + pi] = x[(((size_t)(n * 512 + c0 + ci)) << 12) + p0 + pi];
  }
  __syncthreads();
#pragma unroll
  for (int kk = 0; kk < 16; ++kk) {
    int e = tid + (kk << 8);
    int ci = e & 63, pi = e >> 6;
    float sv = s[ci * 65 + pi] * 1024.f;
    _Float16 hi = (_Float16)sv;
    _Float16 lo = (_Float16)(sv - (float)hi);
    size_t off = (((size_t)(n << 12) + p0 + pi) << 9) + c0 + ci;
    xhi[off] = hi;
    xlo[off] = lo;
  }
}

// ---------------------------------------------------------------------------
// 0c. conv weight convert: [o][c][3][3] f32 -> [t][o][c] f16 hi/lo, x1024.
// ---------------------------------------------------------------------------
__global__ __launch_bounds__(256) void wcvt(const float* __restrict__ w,
                                            _Float16* __restrict__ whi,
                                            _Float16* __restrict__ wlo) {
  const int ct = blockIdx.x, ot = blockIdx.y, t = blockIdx.z;
  const int c0 = ct << 6, o0 = ot << 6;
  const int tid = threadIdx.x;
#pragma unroll
  for (int kk = 0; kk < 16; ++kk) {
    int e = tid + (kk << 8);
    int ci = e & 63, oi = e >> 6;
    float sv = w[(size_t)(o0 + oi) * 4608 + (c0 + ci) * 9 + t] * 1024.f;
    _Float16 hi = (_Float16)sv;
    _Float16 lo = (_Float16)(sv - (float)hi);
    size_t off = ((size_t)((t << 9) + o0 + oi) << 9) + c0 + ci;
    whi[off] = hi;
    wlo[off] = lo;
  }
}

// ---------------------------------------------------------------------------
// 0d. pack 1x1 head weights + biases
// ---------------------------------------------------------------------------
__global__ __launch_bounds__(256) void prep_small(
    const float* __restrict__ lw, const float* __restrict__ sw,
    const float* __restrict__ lb, const float* __restrict__ sb,
    float* __restrict__ wslt, float* __restrict__ wslb) {
  int e = blockIdx.x * 256 + threadIdx.x;
  if (e < 32768) {
    int c = e >> 6, o = e & 63;
    float v = 0.f;
    if (o < 36) v = lw[o * 512 + c];
    else if (o < 54) v = sw[(o - 36) * 512 + c];
    wslt[e] = v;
  } else if (e < 32832) {
    int o = e - 32768;
    float v = 0.f;
    if (o < 36) v = lb[o];
    else if (o < 54) v = sb[o - 36];
    wslb[o] = v;
  }
}

// ---------------------------------------------------------------------------
// 1. MFMA implicit-GEMM 3x3 conv. fp16x2 split (hh + hl + lh), fp32 acc.
// GEMM: M=8192 pixels, N=512 out-ch, K=4608 ordered t-major (9 shifts x 512c).
// Block: 128 pix x 128 o, K-split x2 (kq), 4 waves of 64x64. grid (64,4,2).
// A slab in LDS: [4 rows][68 xs][32 c] f16 (halo + zero-guard); B: [128 o][32 c].
// Epilogue: atomicAdd into zeroed hbuf[n][pix][o] (raw, x2^20 scaled).
// ---------------------------------------------------------------------------
__global__ __launch_bounds__(256) void conv_mfma(
    const _Float16* __restrict__ xhi, const _Float16* __restrict__ xlo,
    const _Float16* __restrict__ whi, const _Float16* __restrict__ wlo,
    const float* __restrict__ guard, float* __restrict__ hout) {
  __shared__ _Float16 aHi[4 * 68 * 32];   // 17408 B
  __shared__ _Float16 aLo[4 * 68 * 32];
  __shared__ _Float16 bHi[128 * 32];      // 8192 B
  __shared__ _Float16 bLo[128 * 32];
  const int tid = threadIdx.x;
  const int lane = tid & 63, w = tid >> 6;
  const int ptile = blockIdx.x;           // 0..63  (pixel tile: 128 px)
  const int og = blockIdx.y;              // 0..3
  const int kq = blockIdx.z;              // 0..1
  const int n = ptile >> 5;
  const int y0 = (ptile & 31) << 1;       // rows y0, y0+1
  const int o0 = og << 7;
  const int l15 = lane & 15, l16 = lane >> 4;
  const int ry = w >> 1;                  // wave pixel-half
  const int wo = (w & 1) << 6;            // wave o-offset

  floatx4 acc[4][4];
#pragma unroll
  for (int a = 0; a < 4; ++a)
#pragma unroll
    for (int b = 0; b < 4; ++b) acc[a][b] = (floatx4)0.f;

  for (int s = 0; s < 8; ++s) {
    const int c0 = (kq << 8) + (s << 5);
    __syncthreads();  // prior slab compute done -> safe to restage A
    // stage A slab: 272 positions (4r x 68xs) x 64B; 17 chunks of 1024B each
    for (int i = w; i < 17; i += 4) {
      int chunk = (i << 6) + lane;        // 0..1087
      int p = chunk >> 2, q = chunk & 3;
      int r = p / 68, xs = p - r * 68;
      int y = y0 - 1 + r, xg = xs - 1;
      bool ok = ((unsigned)y < 64u) && ((unsigned)xg < 64u);
      size_t off = (((size_t)(n << 12) + (y << 6) + xg) << 9) + c0 + (q << 3);
      const void* gh = ok ? (const void*)(xhi + off) : (const void*)guard;
      const void* gl = ok ? (const void*)(xlo + off) : (const void*)guard;
      gl_lds16(gh, (char*)aHi + (i << 10));
      gl_lds16(gl, (char*)aLo + (i << 10));
    }
    for (int tt = 0; tt < 9; ++tt) {
      if (tt > 0) __syncthreads();        // prior t compute done -> restage B
      // stage B: 128 o-rows x 64B = 8 chunks of 1024B
      for (int i = w; i < 8; i += 4) {
        int chunk = (i << 6) + lane;
        int row = chunk >> 2, q = chunk & 3;
        size_t off = ((size_t)((tt << 9) + o0 + row) << 9) + c0 + (q << 3);
        gl_lds16((const void*)(whi + off), (char*)bHi + (i << 10));
        gl_lds16((const void*)(wlo + off), (char*)bLo + (i << 10));
      }
      __syncthreads();                    // drains vmcnt: A(+B) ready

      const int dy = tt / 3, dx = tt - 3 * dy;
      half8 ah[4], al[4], bh[4], bl[4];
#pragma unroll
      for (int im = 0; im < 4; ++im) {
        int xp = (im << 4) + l15;
        int p = (ry + dy) * 68 + xp + dx;
        ah[im] = *(const half8*)&aHi[(p << 5) + (l16 << 3)];
        al[im] = *(const half8*)&aLo[(p << 5) + (l16 << 3)];
      }
#pragma unroll
      for (int in = 0; in < 4; ++in) {
        int orow = wo + (in << 4) + l15;
        bh[in] = *(const half8*)&bHi[(orow << 5) + (l16 << 3)];
        bl[in] = *(const half8*)&bLo[(orow << 5) + (l16 << 3)];
      }
#pragma unroll
      for (int im = 0; im < 4; ++im)
#pragma unroll
        for (int in = 0; in < 4; ++in) {
          acc[im][in] = __builtin_amdgcn_mfma_f32_16x16x32_f16(
              ah[im], bh[in], acc[im][in], 0, 0, 0);
          acc[im][in] = __builtin_amdgcn_mfma_f32_16x16x32_f16(
              ah[im], bl[in], acc[im][in], 0, 0, 0);
          acc[im][in] = __builtin_amdgcn_mfma_f32_16x16x32_f16(
              al[im], bh[in], acc[im][in], 0, 0, 0);
        }
    }
  }

  // epilogue: C[m][n]: m=(lane>>4)*4+reg (pixel), n=lane&15 (channel)
#pragma unroll
  for (int im = 0; im < 4; ++im)
#pragma unroll
    for (int in = 0; in < 4; ++in) {
      int o = o0 + wo + (in << 4) + l15;
#pragma unroll
      for (int reg = 0; reg < 4; ++reg) {
        int m_local = (ry << 6) + (im << 4) + (l16 << 2) + reg;
        size_t off = (((size_t)(n << 12) + (y0 << 6) + m_local) << 9) + o;
        atomicAdd(&hout[off], acc[im][in][reg]);
      }
    }
}

// ---------------------------------------------------------------------------
// 2. 1x1 heads + softmax. grid (64 y, 2 n), block 256.
// hbuf layout now [n][pix][512]; applies x2^-20 scale + bias + relu at load.
// ---------------------------------------------------------------------------
__global__ __launch_bounds__(256) void head_kernel(
    const float* __restrict__ hbuf, const float* __restrict__ cb,
    const float* __restrict__ wslt, const float* __restrict__ wslb,
    float* __restrict__ out, float* __restrict__ fgbuf) {
  const int y = blockIdx.x, n = blockIdx.y;
  __shared__ float sH[16 * 65];
  __shared__ float sWt[1024];
  __shared__ float sOut[64 * 65];
  const int tid = threadIdx.x;
  const int x = tid & 63, og = tid >> 6;

  float acc[16];
#pragma unroll
  for (int j = 0; j < 16; ++j) acc[j] = 0.f;

  const float* hb = hbuf + (((size_t)(n << 12) + (y << 6)) << 9);

  for (int c0 = 0; c0 < 512; c0 += 16) {
    __syncthreads();
#pragma unroll
    for (int p = 0; p < 4; ++p) {
      int e = tid + (p << 8);
      { // sH: e -> cc = e&15 (c contig in global), xx = e>>4
        int cc = e & 15, xx = e >> 4;
        float raw = hb[((size_t)xx << 9) + c0 + cc];
        sH[cc * 65 + xx] = fmaxf(raw * HSCALE + cb[c0 + cc], 0.f);
      }
      { // sWt: e -> cc = e>>6, xx = e&63 (coalesced in wslt)
        int cc = e >> 6, xx = e & 63;
        sWt[e] = wslt[((c0 + cc) << 6) + xx];
      }
    }
    __syncthreads();
#pragma unroll
    for (int cc = 0; cc < 16; ++cc) {
      float hv = sH[cc * 65 + x];
      const float4* wp = (const float4*)&sWt[(cc << 6) + (og << 4)];
      float4 w0 = wp[0], w1 = wp[1], w2 = wp[2], w3 = wp[3];
      acc[0]  = fmaf(hv, w0.x, acc[0]);  acc[1]  = fmaf(hv, w0.y, acc[1]);
      acc[2]  = fmaf(hv, w0.z, acc[2]);  acc[3]  = fmaf(hv, w0.w, acc[3]);
      acc[4]  = fmaf(hv, w1.x, acc[4]);  acc[5]  = fmaf(hv, w1.y, acc[5]);
      acc[6]  = fmaf(hv, w1.z, acc[6]);  acc[7]  = fmaf(hv, w1.w, acc[7]);
      acc[8]  = fmaf(hv, w2.x, acc[8]);  acc[9]  = fmaf(hv, w2.y, acc[9]);
      acc[10] = fmaf(hv, w2.z, acc[10]); acc[11] = fmaf(hv, w2.w, acc[11]);
      acc[12] = fmaf(hv, w3.x, acc[12]); acc[13] = fmaf(hv, w3.y, acc[13]);
      acc[14] = fmaf(hv, w3.z, acc[14]); acc[15] = fmaf(hv, w3.w, acc[15]);
    }
  }
  __syncthreads();
#pragma unroll
  for (int j = 0; j < 16; ++j) {
    int o = (og << 4) + j;
    sOut[o * 65 + x] = acc[j] + wslb[o];
  }
  __syncthreads();

  const int p0 = (n << 12) + (y << 6);
  float* locs = out + O0 + (size_t)p0 * 36;
  for (int e = tid; e < 2304; e += 256) {
    int xx = e / 36, o = e - xx * 36;
    locs[e] = sOut[o * 65 + xx];
  }
  float* scrs = out + O1 + (size_t)p0 * 18;
  for (int e = tid; e < 1152; e += 256) {
    int xx = e / 18, ss = e - xx * 18;
    scrs[e] = sOut[(36 + ss) * 65 + xx];
  }
  float* fg = fgbuf + n * NANCH + (y << 6) * 9;
  for (int e = tid; e < 576; e += 256) {
    int xx = e / 9, a = e - xx * 9;
    float s0 = sOut[(36 + 2 * a) * 65 + xx];
    float s1 = sOut[(36 + 2 * a + 1) * 65 + xx];
    fg[e] = 1.0f / (1.0f + expf(s0 - s1));
  }
}

// ---------------------------------------------------------------------------
// 3. anchors + decode + clip + min-size + sort keys. grid 512, block 256.
// ---------------------------------------------------------------------------
__global__ __launch_bounds__(256) void decode_kernel(
    const float* __restrict__ out0, const float* __restrict__ fgbuf,
    float4* __restrict__ roibuf, u64* __restrict__ keys,
    float* __restrict__ anchor_out,
    const int* __restrict__ imgh_p, const int* __restrict__ imgw_p) {
  int gid = blockIdx.x * 256 + threadIdx.x;   // < 131072
  int n = gid >> 16, k = gid & (SEG - 1);
  if (k >= NANCH) { keys[gid] = ~0ull; return; }
  int a = k % 9;
  int p = k / 9;
  int py = p >> 6, px = p & 63;

  const double R[3] = {0.5, 1.0, 2.0};
  const double S[3] = {8.0, 16.0, 32.0};
  double r = R[a / 3], s = S[a - (a / 3) * 3];
  double hd = 16.0 * s * sqrt(r);
  double wd = 16.0 * s * sqrt(1.0 / r);
  float ay1 = (float)(8.0 - hd / 2.0) + (float)(py * 16);
  float ax1 = (float)(8.0 - wd / 2.0) + (float)(px * 16);
  float ay2 = (float)(8.0 + hd / 2.0) + (float)(py * 16);
  float ax2 = (float)(8.0 + wd / 2.0) + (float)(px * 16);
  if (n == 0) {
    float* ao = anchor_out + (size_t)k * 4;
    ao[0] = ay1; ao[1] = ax1; ao[2] = ay2; ao[3] = ax2;
  }
  float ahk = ay2 - ay1, awk = ax2 - ax1;
  float acy = ay1 + 0.5f * ahk, acx = ax1 + 0.5f * awk;
  const float* lp = out0 + ((size_t)(n * NANCH + k) << 2);
  float dy = lp[0], dx = lp[1], dh = lp[2], dw = lp[3];
  float cy = dy * ahk + acy;
  float cx = dx * awk + acx;
  float bh = expf(dh) * ahk;
  float bw = expf(dw) * awk;
  float img_h = (float)imgh_p[0], img_w = (float)imgw_p[0];
  float y1 = fminf(fmaxf(cy - 0.5f * bh, 0.f), img_h);
  float x1 = fminf(fmaxf(cx - 0.5f * bw, 0.f), img_w);
  float y2 = fminf(fmaxf(cy + 0.5f * bh, 0.f), img_h);
  float x2 = fminf(fmaxf(cx + 0.5f * bw, 0.f), img_w);
  bool valid = ((y2 - y1) >= 16.f) && ((x2 - x1) >= 16.f);
  float sc = valid ? fgbuf[n * NANCH + k] : -INFINITY;
  roibuf[n * NANCH + k] = make_float4(y1, x1, y2, x2);
  unsigned int b = __float_as_uint(sc);
  unsigned int m = b ^ ((b & 0x80000000u) ? 0xFFFFFFFFu : 0x80000000u);
  keys[gid] = ((u64)(~m) << 32) | (unsigned int)k;
}

// ---------------------------------------------------------------------------
// 4. init rois/roi_indices/vmask
// ---------------------------------------------------------------------------
__global__ __launch_bounds__(256) void init_out(float* __restrict__ out) {
  int e = blockIdx.x * 256 + threadIdx.x;
  if (e < 2400) out[O2 + e] = 0.f;
  else if (e < 3000) out[O3 + (e - 2400)] = (float)((e - 2400) / 300);
  else if (e < 3600) out[O5 + (e - 3000)] = 0.f;
}

// ---------------------------------------------------------------------------
// 5. bitonic sort (u64 keys, ascending per 65536 segment), 11 launches
// ---------------------------------------------------------------------------
__global__ __launch_bounds__(256) void sort_local_a(u64* __restrict__ keys) {
  __shared__ u64 sk[4096];
  const int base = blockIdx.x << 12;
  for (int e = threadIdx.x; e < 4096; e += 256) sk[e] = keys[base + e];
  __syncthreads();
  for (int k = 2; k <= 4096; k <<= 1) {
    for (int j = k >> 1; j > 0; j >>= 1) {
      for (int t = threadIdx.x; t < 2048; t += 256) {
        int l = ((t & ~(j - 1)) << 1) | (t & (j - 1));
        int rr = l | j;
        bool asc = (((base + l) & k) == 0);
        u64 a = sk[l], b = sk[rr];
        if ((a > b) == asc) { sk[l] = b; sk[rr] = a; }
      }
      __syncthreads();
    }
  }
  for (int e = threadIdx.x; e < 4096; e += 256) keys[base + e] = sk[e];
}

__global__ __launch_bounds__(256) void sort_global_pass(u64* __restrict__ keys,
                                                        int k, int j) {
  int t = blockIdx.x * 256 + threadIdx.x;
  int l = ((t & ~(j - 1)) << 1) | (t & (j - 1));
  int rr = l | j;
  bool asc = (((l & (SEG - 1)) & k) == 0);
  u64 a = keys[l], b = keys[rr];
  if ((a > b) == asc) { keys[l] = b; keys[rr] = a; }
}

__global__ __launch_bounds__(256) void sort_global_pass2(u64* __restrict__ keys,
                                                         int k, int j1) {
  int t = blockIdx.x * 256 + threadIdx.x;
  int j2 = j1 >> 1;
  int l = ((t & ~(j2 - 1)) << 1) | (t & (j2 - 1));
  l = ((l & ~(j1 - 1)) << 1) | (l & (j1 - 1));
  u64 e0 = keys[l], e1 = keys[l | j2], e2 = keys[l | j1], e3 = keys[l | j1 | j2];
  bool asc = (((l & (SEG - 1)) & k) == 0);
  u64 tmp;
  if ((e0 > e2) == asc) { tmp = e0; e0 = e2; e2 = tmp; }
  if ((e1 > e3) == asc) { tmp = e1; e1 = e3; e3 = tmp; }
  if ((e0 > e1) == asc) { tmp = e0; e0 = e1; e1 = tmp; }
  if ((e2 > e3) == asc) { tmp = e2; e2 = e3; e3 = tmp; }
  keys[l] = e0; keys[l | j2] = e1; keys[l | j1] = e2; keys[l | j1 | j2] = e3;
}

__global__ __launch_bounds__(256) void sort_local_b(u64* __restrict__ keys, int k) {
  __shared__ u64 sk[4096];
  const int base = blockIdx.x << 12;
  for (int e = threadIdx.x; e < 4096; e += 256) sk[e] = keys[base + e];
  __syncthreads();
  for (int j = 2048; j > 0; j >>= 1) {
    for (int t = threadIdx.x; t < 2048; t += 256) {
      int l = ((t & ~(j - 1)) << 1) | (t & (j - 1));
      int rr = l | j;
      bool asc = ((((base + l) & (SEG - 1)) & k) == 0);
      u64 a = sk[l], b = sk[rr];
      if ((a > b) == asc) { sk[l] = b; sk[rr] = a; }
    }
    __syncthreads();
  }
  for (int e = threadIdx.x; e < 4096; e += 256) keys[base + e] = sk[e];
}

// ---------------------------------------------------------------------------
// 6. chunked greedy NMS, one wave per image
// ---------------------------------------------------------------------------
__global__ __launch_bounds__(64) void nms_kernel(
    const u64* __restrict__ keys, const float4* __restrict__ roibuf,
    float* __restrict__ out) {
  const int n = blockIdx.x;
  const int lane = threadIdx.x;
  __shared__ float kb_y1[N_POST], kb_x1[N_POST], kb_y2[N_POST], kb_x2[N_POST],
      kb_a[N_POST];
  float* rois = out + O2 + n * (N_POST * 4);
  float* vmask = out + O5 + n * N_POST;
  const u64* kseg = keys + ((size_t)n << 16);
  const float4* rseg = roibuf + (size_t)n * NANCH;
  int nk = 0;

  for (int c0 = 0; c0 < N_PRE && nk < N_POST; c0 += 64) {
    int i = c0 + lane;
    u64 kk = (i < N_PRE) ? kseg[i] : ~0ull;
    bool valid = ((unsigned)(kk >> 32)) < 0xFF800000u;
    float4 bx = make_float4(0.f, 0.f, 0.f, 0.f);
    if (valid) bx = rseg[(unsigned)(kk & 0xFFFFFFFFu)];
    float area = (bx.z - bx.x) * (bx.w - bx.y);

    bool sup = false;
    for (int j = 0; j < nk && !sup; ++j) {
      float ih = fmaxf(fminf(bx.z, kb_y2[j]) - fmaxf(bx.x, kb_y1[j]), 0.f);
      float iw = fmaxf(fminf(bx.w, kb_x2[j]) - fmaxf(bx.y, kb_x1[j]), 0.f);
      float inter = ih * iw;
      sup = inter / (area + kb_a[j] - inter + 1e-9f) > 0.7f;
    }
    u64 alive = __ballot(valid) & ~__ballot(sup);

    u64 supmask = 0;
    for (int j = 0; j < 64; ++j) {
      float jy1 = __shfl(bx.x, j), jx1 = __shfl(bx.y, j);
      float jy2 = __shfl(bx.z, j), jx2 = __shfl(bx.w, j);
      float ja = __shfl(area, j);
      float ih = fmaxf(fminf(bx.z, jy2) - fmaxf(bx.x, jy1), 0.f);
      float iw = fmaxf(fminf(bx.w, jx2) - fmaxf(bx.y, jx1), 0.f);
      float inter = ih * iw;
      bool bit = (inter / (area + ja - inter + 1e-9f) > 0.7f) && (j < lane);
      supmask |= ((u64)bit) << j;
    }

    u64 kept = 0;
    for (int j = 0; j < 64; ++j) {
      u64 smj = __shfl(supmask, j);
      bool kj = ((alive >> j) & 1ull) && ((smj & kept) == 0ull);
      kept |= ((u64)kj) << j;
    }

    u64 below = (lane == 0) ? 0ull : (~0ull >> (64 - lane));
    int rank = __popcll(kept & below);
    if ((kept >> lane) & 1ull) {
      int slot = nk + rank;
      if (slot < N_POST) {
        kb_y1[slot] = bx.x; kb_x1[slot] = bx.y;
        kb_y2[slot] = bx.z; kb_x2[slot] = bx.w; kb_a[slot] = area;
        rois[slot * 4 + 0] = bx.x; rois[slot * 4 + 1] = bx.y;
        rois[slot * 4 + 2] = bx.z; rois[slot * 4 + 3] = bx.w;
        vmask[slot] = 1.0f;
      }
    }
    nk += __popcll(kept);
    if (nk > N_POST) nk = N_POST;
    __syncthreads();
    if (__ballot(valid) == 0) break;
  }
}

// ---------------------------------------------------------------------------
extern "C" void kernel_launch(void* const* d_in, const int* in_sizes, int n_in,
                              void* d_out, int out_size, void* d_ws, size_t ws_size,
                              hipStream_t stream) {
  const float* x        = (const float*)d_in[0];
  const float* conv1_w  = (const float*)d_in[1];
  const float* conv1_b  = (const float*)d_in[2];
  const float* score_w  = (const float*)d_in[3];
  const float* score_b  = (const float*)d_in[4];
  const float* loc_w    = (const float*)d_in[5];
  const float* loc_b    = (const float*)d_in[6];
  const int*   imgh_p   = (const int*)d_in[7];
  const int*   imgw_p   = (const int*)d_in[8];

  float* out = (float*)d_out;
  float* ws  = (float*)d_ws;

  _Float16* xhi = (_Float16*)(ws + WS_XHI);
  _Float16* xlo = (_Float16*)(ws + WS_XLO);
  _Float16* whi = (_Float16*)(ws + WS_WHI);
  _Float16* wlo = (_Float16*)(ws + WS_WLO);
  float* wslt   = ws + WS_WSLT;
  float* wslb   = ws + WS_WSLB;
  float* hbuf   = ws + WS_H;
  float* guard  = ws + WS_GUARD;
  // overlays (valid only after conv_mfma completes; xhi region is dead then)
  float* fgbuf   = ws + WS_FG;
  float4* roibuf = (float4*)(ws + WS_ROI);
  u64* keys      = (u64*)(ws + WS_KEYS);

  zero_h<<<4097, 256, 0, stream>>>((float4*)hbuf, (float4*)guard);
  xcvt<<<dim3(64, 8, 2), 256, 0, stream>>>(x, xhi, xlo);
  wcvt<<<dim3(8, 8, 9), 256, 0, stream>>>(conv1_w, whi, wlo);
  prep_small<<<129, 256, 0, stream>>>(loc_w, score_w, loc_b, score_b, wslt, wslb);

  conv_mfma<<<dim3(64, 4, 2), 256, 0, stream>>>(xhi, xlo, whi, wlo, guard, hbuf);

  head_kernel<<<dim3(64, 2), 256, 0, stream>>>(hbuf, conv1_b, wslt, wslb, out, fgbuf);
  decode_kernel<<<512, 256, 0, stream>>>(out, fgbuf, roibuf, keys,
                                         out + O4, imgh_p, imgw_p);
  init_out<<<15, 256, 0, stream>>>(out);

  sort_local_a<<<32, 256, 0, stream>>>(keys);
  for (int k = 8192; k <= SEG; k <<= 1) {
    int j = k >> 1;
    while (j >= 4096) {
      if (j >= 8192) {
        sort_global_pass2<<<128, 256, 0, stream>>>(keys, k, j);
        j >>= 2;
      } else {
        sort_global_pass<<<256, 256, 0, stream>>>(keys, k, j);
        j >>= 1;
      }
    }
    sort_local_b<<<32, 256, 0, stream>>>(keys, k);
  }

  nms_kernel<<<2, 64, 0, stream>>>(keys, roibuf, out);
}